// Round 8
// baseline (145.218 us; speedup 1.0000x reference)
//
#include <hip/hip_runtime.h>

// Problem constants
#define B_    16
#define N_    1024
#define DIN_  256
#define H_    4
#define F_    64
#define COUT_ 256
#define NEG_  0.2f
#define LOG2E_ 1.4426950408889634f

typedef __bf16 bf16x8 __attribute__((ext_vector_type(8)));
typedef float  f32x4  __attribute__((ext_vector_type(4)));
typedef unsigned short u16x8 __attribute__((ext_vector_type(8)));
typedef unsigned short u16x4 __attribute__((ext_vector_type(4)));
typedef unsigned int   u32x4 __attribute__((ext_vector_type(4)));

__device__ __forceinline__ unsigned short f2bf(float f) {
    unsigned u = __builtin_bit_cast(unsigned, f);
    u += 0x7fffu + ((u >> 16) & 1u);
    return (unsigned short)(u >> 16);
}

// ---------------------------------------------------------------------------
// Prep: pack W into MFMA-B-frag order Wtp, bf16 (1KB-contiguous frag loads).
// ---------------------------------------------------------------------------
__global__ __launch_bounds__(256) void prep_kernel(
    const float* __restrict__ W, unsigned short* __restrict__ Wtp) {
    const int c = blockIdx.x, k = threadIdx.x;
    const int w = c >> 6, ft = (c >> 4) & 3, l15 = c & 15;
    const int it = k >> 5, q = (k >> 3) & 3, jj = k & 7;
    const int ln = q * 16 + l15;
    Wtp[((((w * 8 + it) * 4 + ft) * 64) + ln) * 8 + jj] = f2bf(W[k * COUT_ + c]);
}

// ---------------------------------------------------------------------------
// Stage kernel (R13): gat_h ONLY — the masker pass is deleted; the bitmask
// is now built inside gat_attn from a coalesced one-shot adj staging (the
// attn grid partitions adj exactly: block (b,it0) needs precisely rows
// [it0,it0+32) of batch b). R5-R7 showed the separate masker stuck at ~30us
// (3x its 11us stream floor) across three rewrites; its 64MB stream now
// lives inside attn where it is read ONCE, coalesced, and overlaps heads.
// gat_h body unchanged (R5 numerics). Grid: 1024 blocks x 256 threads.
// ---------------------------------------------------------------------------
__global__ __launch_bounds__(256, 4) void stage_kernel(
    const float* __restrict__ x, const unsigned short* __restrict__ Wtp,
    const float* __restrict__ a_src, const float* __restrict__ a_dst,
    unsigned short* __restrict__ hp, float* __restrict__ e_src,
    float* __restrict__ e_dst) {
    __shared__ unsigned short xs[16][264];   // bf16 bits; padded row stride
    const int w  = threadIdx.x >> 6;
    const int ln = threadIdx.x & 63;

    const int blk = blockIdx.x;
    const int b   = blk & 15;
    const int it0 = (blk >> 4) * 16;
    const int l15 = ln & 15;
    const int q   = ln >> 4;

#pragma unroll
    for (int s = 0; s < 4; s++) {
        const int row = w * 4 + s;
        f32x4 xv = *(const f32x4*)(x + (size_t)(b * N_ + it0 + row) * DIN_ + ln * 4);
        unsigned lo = (unsigned)f2bf(xv[0]) | ((unsigned)f2bf(xv[1]) << 16);
        unsigned hi = (unsigned)f2bf(xv[2]) | ((unsigned)f2bf(xv[3]) << 16);
        unsigned long long hb = (unsigned long long)lo | ((unsigned long long)hi << 32);
        *(unsigned long long*)&xs[row][ln * 4] = hb;
    }
    __syncthreads();

    f32x4 acc[4];
#pragma unroll
    for (int ft = 0; ft < 4; ft++) acc[ft] = (f32x4)0.0f;

    const unsigned short* wb = Wtp + (w * 8) * 4 * 64 * 8 + ln * 8;
#pragma unroll
    for (int it = 0; it < 8; it++) {
        bf16x8 af = *(const bf16x8*)&xs[l15][it * 32 + q * 8];
#pragma unroll
        for (int ft = 0; ft < 4; ft++) {
            bf16x8 bf = *((const bf16x8*)(wb + (it * 4 + ft) * 512));
            acc[ft] = __builtin_amdgcn_mfma_f32_16x16x32_bf16(af, bf, acc[ft], 0, 0, 0);
        }
    }

    // Store hp frag-packed (R5 layout). Lane holds h[i=it0+q*4+r][f=ft*16+l15].
    const int jg = it0 >> 5;
    const int q2 = 2 * ((it0 >> 4) & 1) + (q >> 1);
#pragma unroll
    for (int ft = 0; ft < 4; ft++) {
        u16x4 hb;
#pragma unroll
        for (int r = 0; r < 4; r++) hb[r] = f2bf(acc[ft][r]);
        const size_t addr =
            (size_t)((((b * H_ + w) * 32 + jg) * 4 + ft) * 64 + q2 * 16 + l15) * 8 + (q & 1) * 4;
        *((u16x4*)(hp + addr)) = hb;
    }

    // e logits from fp32 acc (x log2e), stored f32 (R5 path).
    float as_v[4], ad_v[4];
#pragma unroll
    for (int ft = 0; ft < 4; ft++) {
        as_v[ft] = a_src[w * F_ + ft * 16 + l15];
        ad_v[ft] = a_dst[w * F_ + ft * 16 + l15];
    }
    float ps[4], pd[4];
#pragma unroll
    for (int r = 0; r < 4; r++) {
        ps[r] = 0.0f; pd[r] = 0.0f;
#pragma unroll
        for (int ft = 0; ft < 4; ft++) {
            ps[r] += acc[ft][r] * as_v[ft];
            pd[r] += acc[ft][r] * ad_v[ft];
        }
    }
#pragma unroll
    for (int off = 1; off <= 8; off <<= 1)
#pragma unroll
        for (int r = 0; r < 4; r++) {
            ps[r] += __shfl_xor(ps[r], off);
            pd[r] += __shfl_xor(pd[r], off);
        }
    float vs = (l15 == 0) ? ps[0] : (l15 == 1) ? ps[1] : (l15 == 2) ? ps[2] : ps[3];
    float vd = (l15 == 0) ? pd[0] : (l15 == 1) ? pd[1] : (l15 == 2) ? pd[2] : pd[3];
    if (l15 < 4) {
        const int i = it0 + q * 4 + l15;
        e_src[(b * H_ + w) * N_ + i] = vs * LOG2E_;
        e_dst[(b * H_ + w) * N_ + i] = vd * LOG2E_;
    }
}

// ---------------------------------------------------------------------------
// Kernel C (R13): in-kernel ballot mask + fused leaky/exp2 + (P @ h) MFMA
// + normalize + bias. R12 body; mask staging replaced by COALESCED adj
// ballot staging (the R2 failure was a per-jg 16-row GATHER; this is a
// one-shot stream):
//   wave w8 stages rows w8*4 + (ln>>4); per iter, lane reads f32x4 at
//   float offset it*64 + (ln&15)*4 (16 lanes x 16B = 256B contiguous per
//   row, 4 rows per inst); 4 ballots/iter; lanes 0..7 assemble words via
//   R12's byte-extract (word jg bit (8e+t) <-> j = jg*32+4t+e) -> mk_s.
//   bp0/bp1 gate bits IDENTICAL to R12. unroll 4 bounds VGPR (R3 lesson).
// Deletes: masker pass (~30us), mask buffer, mask round-trip. Adds: 64MB
// adj read-once inside attn (~11us BW floor).
// ---------------------------------------------------------------------------
__global__ __launch_bounds__(512, 4) void gat_attn_kernel(
    const float* __restrict__ adj, const unsigned short* __restrict__ hp,
    const float* __restrict__ e_src, const float* __restrict__ e_dst,
    const float* __restrict__ bias, float* __restrict__ out) {
    const int lid = ((blockIdx.x & 7) << 6) | (blockIdx.x >> 3);  // XCD swizzle
    const int b   = lid >> 5;
    const int it0 = (lid & 31) * 32;
    const int w8  = threadIdx.x >> 6;
    const int h   = w8 & 3;             // head
    const int jh  = w8 >> 2;            // j-half
    const int ln  = threadIdx.x & 63;
    const int l15 = ln & 15;
    const int q   = ln >> 4;

    __shared__ float lds[H_][2][5][64][4];   // 40 KB: acc[2][4] + accs[2]
    __shared__ float es_s[H_][N_];           // 16 KB: e_src all 4 heads
    __shared__ unsigned mk_s[32][37];        // ~4.6 KB: mask words [i'][jg], padded

    // ---- cooperative staging: es tiles + in-kernel ballot mask ----
    {
        const int tid = threadIdx.x;
#pragma unroll
        for (int p = 0; p < 2; p++) {
            const int c  = p * 512 + tid;        // 0..1023 f32x4-chunks
            const int h_ = c >> 8;
            const int of = (c & 255) * 4;
            *(f32x4*)&es_s[h_][of] =
                *(const f32x4*)(e_src + (size_t)(b * H_ + h_) * N_ + of);
        }
        // adj ballot staging: wave w8 covers rows w8*4 .. w8*4+3
        const int r4 = ln >> 4;                  // row within wave (0..3)
        const float* arow =
            adj + (size_t)(b * N_ + it0 + w8 * 4 + r4) * N_ + l15 * 4;
#pragma unroll 4
        for (int it = 0; it < 16; it++) {
            f32x4 v = *(const f32x4*)(arow + it * 64);
            unsigned long long bal[4];
#pragma unroll
            for (int e = 0; e < 4; e++) bal[e] = __ballot(v[e] > 0.5f);
            if (ln < 8) {
                // lane L: row r=L>>1, half=L&1; byte L of each ballot.
                unsigned wd = 0;
#pragma unroll
                for (int e = 0; e < 4; e++)
                    wd |= ((unsigned)((bal[e] >> (8 * ln)) & 0xffull)) << (8 * e);
                mk_s[w8 * 4 + (ln >> 1)][2 * it + (ln & 1)] = wd;
            }
        }
    }

    float edv[2];
    edv[0] = e_dst[(b * H_ + h) * N_ + it0 + l15];
    edv[1] = e_dst[(b * H_ + h) * N_ + it0 + 16 + l15];

    const unsigned short* hp_base = hp + (size_t)((b * H_ + h) * 32) * 2048 + ln * 8;

    f32x4 acc[2][4];
    f32x4 accs[2];
#pragma unroll
    for (int mt = 0; mt < 2; mt++) {
#pragma unroll
        for (int ft = 0; ft < 4; ft++) acc[mt][ft] = (f32x4)0.0f;
        accs[mt] = (f32x4)0.0f;
    }

    u16x8 ones_u;
#pragma unroll
    for (int jj = 0; jj < 8; jj++) ones_u[jj] = 0x3F80;   // bf16 1.0
    const bf16x8 ones = __builtin_bit_cast(bf16x8, ones_u);

    // ---- hp register double-buffer: prefetch jg0 ----
    const unsigned short* hf0 = hp_base + (size_t)(jh * 16) * 2048;
    bf16x8 nb0 = *((const bf16x8*)(hf0 + 0 * 512));
    bf16x8 nb1 = *((const bf16x8*)(hf0 + 1 * 512));
    bf16x8 nb2 = *((const bf16x8*)(hf0 + 2 * 512));
    bf16x8 nb3 = *((const bf16x8*)(hf0 + 3 * 512));

    __syncthreads();   // es_s/mk_s ready

    const int bp0[4] = {0, 16, 1, 17};
    const int bp1[4] = {8, 24, 9, 25};

#pragma unroll
    for (int t = 0; t < 16; t++) {
        const int jg = jh * 16 + t;
        const bf16x8 cb0 = nb0, cb1 = nb1, cb2 = nb2, cb3 = nb3;
        if (t < 15) {   // issue next-jg hp loads before this jg's compute
            const unsigned short* hfn = hp_base + (size_t)(jg + 1) * 2048;
            nb0 = *((const bf16x8*)(hfn + 0 * 512));
            nb1 = *((const bf16x8*)(hfn + 1 * 512));
            nb2 = *((const bf16x8*)(hfn + 2 * 512));
            nb3 = *((const bf16x8*)(hfn + 3 * 512));
        }

        f32x4 e0 = *(const f32x4*)&es_s[h][jg * 32 + q * 8];
        f32x4 e1 = *(const f32x4*)&es_s[h][jg * 32 + q * 8 + 4];
        const unsigned w0 = mk_s[l15][jg] >> (2 * q);
        const unsigned w1 = mk_s[16 + l15][jg] >> (2 * q);

        float es8[8] = {e0[0], e0[1], e0[2], e0[3], e1[0], e1[1], e1[2], e1[3]};

        bf16x8 afr[2];
#pragma unroll
        for (int mt = 0; mt < 2; mt++) {
            const unsigned mw = mt ? w1 : w0;
            u32x4 up;
#pragma unroll
            for (int p2 = 0; p2 < 4; p2++) {
                float t0 = edv[mt] + es8[2 * p2];
                float t1 = edv[mt] + es8[2 * p2 + 1];
                t0 = fmaxf(t0, NEG_ * t0);                 // leaky (log2-space)
                t1 = fmaxf(t1, NEG_ * t1);
                float p0 = __builtin_amdgcn_exp2f(t0);
                float p1 = __builtin_amdgcn_exp2f(t1);
                p0 = ((mw >> bp0[p2]) & 1u) ? p0 : 0.0f;
                p1 = ((mw >> bp1[p2]) & 1u) ? p1 : 0.0f;
                up[p2] = __builtin_amdgcn_perm(__builtin_bit_cast(unsigned, p1),
                                               __builtin_bit_cast(unsigned, p0),
                                               0x07060302u);
            }
            afr[mt] = __builtin_bit_cast(bf16x8, up);
        }
#pragma unroll
        for (int mt = 0; mt < 2; mt++) {
            acc[mt][0] = __builtin_amdgcn_mfma_f32_16x16x32_bf16(afr[mt], cb0, acc[mt][0], 0, 0, 0);
            acc[mt][1] = __builtin_amdgcn_mfma_f32_16x16x32_bf16(afr[mt], cb1, acc[mt][1], 0, 0, 0);
            acc[mt][2] = __builtin_amdgcn_mfma_f32_16x16x32_bf16(afr[mt], cb2, acc[mt][2], 0, 0, 0);
            acc[mt][3] = __builtin_amdgcn_mfma_f32_16x16x32_bf16(afr[mt], cb3, acc[mt][3], 0, 0, 0);
            accs[mt]   = __builtin_amdgcn_mfma_f32_16x16x32_bf16(afr[mt], ones, accs[mt], 0, 0, 0);
        }
    }

    // Cross-j-half combine via LDS.
    if (jh == 1) {
#pragma unroll
        for (int mt = 0; mt < 2; mt++) {
#pragma unroll
            for (int ft = 0; ft < 4; ft++)
                *(f32x4*)&lds[h][mt][ft][ln][0] = acc[mt][ft];
            *(f32x4*)&lds[h][mt][4][ln][0] = accs[mt];
        }
    }
    __syncthreads();
    if (jh == 0) {
#pragma unroll
        for (int mt = 0; mt < 2; mt++) {
#pragma unroll
            for (int ft = 0; ft < 4; ft++)
                acc[mt][ft] += *(const f32x4*)&lds[h][mt][ft][ln][0];
            accs[mt] += *(const f32x4*)&lds[h][mt][4][ln][0];
        }
        float bias_v[4];
#pragma unroll
        for (int ft = 0; ft < 4; ft++) bias_v[ft] = bias[h * F_ + ft * 16 + l15];
#pragma unroll
        for (int mt = 0; mt < 2; mt++) {
            f32x4 rinv;
#pragma unroll
            for (int r = 0; r < 4; r++) rinv[r] = 1.0f / accs[mt][r];
#pragma unroll
            for (int ft = 0; ft < 4; ft++)
#pragma unroll
                for (int r = 0; r < 4; r++) {
                    const int i = it0 + mt * 16 + q * 4 + r;
                    const int c = h * F_ + ft * 16 + l15;
                    out[(size_t)(b * N_ + i) * COUT_ + c] = acc[mt][ft][r] * rinv[r] + bias_v[ft];
                }
        }
    }
}

// ---------------------------------------------------------------------------
// Workspace layout (bytes):
//   [0, 128K)    Wtp  bf16 frag-packed [256][256]
//   [128K, +8M)  hp   bf16 frag-packed [B][H][32][4][64][8]
//   +8M: e_src f32 (256K), e_dst f32 (256K). (mask buffer deleted in R13.)
// ---------------------------------------------------------------------------
extern "C" void kernel_launch(void* const* d_in, const int* in_sizes, int n_in,
                              void* d_out, int out_size, void* d_ws, size_t ws_size,
                              hipStream_t stream) {
    const float* x     = (const float*)d_in[0];
    const float* adj   = (const float*)d_in[1];
    const float* W     = (const float*)d_in[2];
    const float* a_src = (const float*)d_in[3];
    const float* a_dst = (const float*)d_in[4];
    const float* bias  = (const float*)d_in[5];
    float* out = (float*)d_out;

    char* ws = (char*)d_ws;
    unsigned short* Wtp = (unsigned short*)ws;
    unsigned short* hp  = (unsigned short*)(ws + 131072);
    float* e_src        = (float*)(ws + 131072 + 8388608);
    float* e_dst        = (float*)(ws + 131072 + 8388608 + 262144);

    prep_kernel<<<256, 256, 0, stream>>>(W, Wtp);
    stage_kernel<<<1024, 256, 0, stream>>>(x, Wtp, a_src, a_dst, hp, e_src, e_dst);
    gat_attn_kernel<<<512, 512, 0, stream>>>(adj, hp, e_src, e_dst, bias, out);
}

// Round 9
// 143.576 us; speedup vs baseline: 1.0114x; 1.0114x over previous
//
#include <hip/hip_runtime.h>

// Problem constants
#define B_    16
#define N_    1024
#define DIN_  256
#define H_    4
#define F_    64
#define COUT_ 256
#define NEG_  0.2f
#define LOG2E_ 1.4426950408889634f

typedef __bf16 bf16x8 __attribute__((ext_vector_type(8)));
typedef float  f32x4  __attribute__((ext_vector_type(4)));
typedef unsigned short u16x8 __attribute__((ext_vector_type(8)));
typedef unsigned short u16x4 __attribute__((ext_vector_type(4)));
typedef unsigned int   u32x4 __attribute__((ext_vector_type(4)));

__device__ __forceinline__ unsigned short f2bf(float f) {
    unsigned u = __builtin_bit_cast(unsigned, f);
    u += 0x7fffu + ((u >> 16) & 1u);
    return (unsigned short)(u >> 16);
}

// ---------------------------------------------------------------------------
// Prep: pack W into MFMA-B-frag order Wtp, bf16 (1KB-contiguous frag loads).
// ---------------------------------------------------------------------------
__global__ __launch_bounds__(256) void prep_kernel(
    const float* __restrict__ W, unsigned short* __restrict__ Wtp) {
    const int c = blockIdx.x, k = threadIdx.x;
    const int w = c >> 6, ft = (c >> 4) & 3, l15 = c & 15;
    const int it = k >> 5, q = (k >> 3) & 3, jj = k & 7;
    const int ln = q * 16 + l15;
    Wtp[((((w * 8 + it) * 4 + ft) * 64) + ln) * 8 + jj] = f2bf(W[k * COUT_ + c]);
}

// ---------------------------------------------------------------------------
// Stage kernel — R14 deep-MLP masker + 1:1 interleave with gat_h.
// Evidence: three masker variants (R5/R7/R13) all cost ~25-30us with VALU
// ~4us, HBM-stream ~10us floors => latency-throttled; the invariant across
// all three was only ~4 outstanding 1KB loads/wave. R14 changes exactly
// that: each masker wave owns 4 ROWS, issues ALL 16 loads (16KB) up-front
// into distinct regs (no reuse -> no forced drain), then processes per-row
// with the R7 ballot/byte-extract and i-major coalesced store (bit layout
// identical to R12 -> attn unchanged). Grid: 2048 blocks, even = masker
// (1024: 16 rows/block), odd = gat_h (1024, body verbatim) so every CU
// generation mixes MFMA waves into masker stalls.
// ---------------------------------------------------------------------------
__global__ __launch_bounds__(256, 4) void stage_kernel(
    const float* __restrict__ adj, const float* __restrict__ x,
    const unsigned short* __restrict__ Wtp, const float* __restrict__ a_src,
    const float* __restrict__ a_dst, unsigned int* __restrict__ mask,
    unsigned short* __restrict__ hp, float* __restrict__ e_src,
    float* __restrict__ e_dst) {
    __shared__ unsigned short xs[16][264];   // bf16 bits; padded row stride
    const int w  = threadIdx.x >> 6;
    const int ln = threadIdx.x & 63;

    if ((blockIdx.x & 1) == 0) {
        // ---- masker: 4 rows/wave, 16 loads in flight, ballot bits ----
        const int mblk = blockIdx.x >> 1;            // 0..1023
        const int row0 = mblk * 16 + w * 4;          // b*N + i base, 4 rows
        const float* ar = adj + (size_t)row0 * N_ + ln * 4;

        f32x4 v[4][4];
#pragma unroll
        for (int r = 0; r < 4; r++)
#pragma unroll
            for (int c = 0; c < 4; c++)
                v[r][c] = *(const f32x4*)(ar + (size_t)r * N_ + c * 256);

#pragma unroll
        for (int r = 0; r < 4; r++) {
            // 16 ballots: bal[c][e] bit ln <-> adj[row][c*256+ln*4+e] > 0.5
            unsigned long long bal[4][4];
#pragma unroll
            for (int e = 0; e < 4; e++) {
                bal[0][e] = __ballot(v[r][0][e] > 0.5f);
                bal[1][e] = __ballot(v[r][1][e] > 0.5f);
                bal[2][e] = __ballot(v[r][2][e] > 0.5f);
                bal[3][e] = __ballot(v[r][3][e] > 0.5f);
            }
            // lane ln<32 assembles word jg=ln: c=ln>>3, byte ln&7 of each
            // ballot -> word bit (8e+t) <-> j = jg*32 + 4t + e.  [R7/R12]
            const int c_ = (ln >> 3) & 3;
            const int sh = (ln & 7) * 8;
            unsigned wd = 0;
#pragma unroll
            for (int e = 0; e < 4; e++) {
                unsigned long long be = (c_ == 0) ? bal[0][e]
                                      : (c_ == 1) ? bal[1][e]
                                      : (c_ == 2) ? bal[2][e] : bal[3][e];
                wd |= ((unsigned)((be >> sh) & 0xffull)) << (8 * e);
            }
            if (ln < 32)
                mask[(size_t)(row0 + r) * 32 + ln] = wd;
        }
    } else {
        // ---- gat_h part (bf16, R5 numerics, LDS-staged x; verbatim) ----
        const int blk = blockIdx.x >> 1;             // 0..1023
        const int b   = blk & 15;
        const int it0 = (blk >> 4) * 16;
        const int l15 = ln & 15;
        const int q   = ln >> 4;

#pragma unroll
        for (int s = 0; s < 4; s++) {
            const int row = w * 4 + s;
            f32x4 xv = *(const f32x4*)(x + (size_t)(b * N_ + it0 + row) * DIN_ + ln * 4);
            unsigned lo = (unsigned)f2bf(xv[0]) | ((unsigned)f2bf(xv[1]) << 16);
            unsigned hi = (unsigned)f2bf(xv[2]) | ((unsigned)f2bf(xv[3]) << 16);
            unsigned long long hb = (unsigned long long)lo | ((unsigned long long)hi << 32);
            *(unsigned long long*)&xs[row][ln * 4] = hb;
        }
        __syncthreads();

        f32x4 acc[4];
#pragma unroll
        for (int ft = 0; ft < 4; ft++) acc[ft] = (f32x4)0.0f;

        const unsigned short* wb = Wtp + (w * 8) * 4 * 64 * 8 + ln * 8;
#pragma unroll
        for (int it = 0; it < 8; it++) {
            bf16x8 af = *(const bf16x8*)&xs[l15][it * 32 + q * 8];
#pragma unroll
            for (int ft = 0; ft < 4; ft++) {
                bf16x8 bf = *((const bf16x8*)(wb + (it * 4 + ft) * 512));
                acc[ft] = __builtin_amdgcn_mfma_f32_16x16x32_bf16(af, bf, acc[ft], 0, 0, 0);
            }
        }

        const int jg = it0 >> 5;
        const int q2 = 2 * ((it0 >> 4) & 1) + (q >> 1);
#pragma unroll
        for (int ft = 0; ft < 4; ft++) {
            u16x4 hb;
#pragma unroll
            for (int r = 0; r < 4; r++) hb[r] = f2bf(acc[ft][r]);
            const size_t addr =
                (size_t)((((b * H_ + w) * 32 + jg) * 4 + ft) * 64 + q2 * 16 + l15) * 8 + (q & 1) * 4;
            *((u16x4*)(hp + addr)) = hb;
        }

        float as_v[4], ad_v[4];
#pragma unroll
        for (int ft = 0; ft < 4; ft++) {
            as_v[ft] = a_src[w * F_ + ft * 16 + l15];
            ad_v[ft] = a_dst[w * F_ + ft * 16 + l15];
        }
        float ps[4], pd[4];
#pragma unroll
        for (int r = 0; r < 4; r++) {
            ps[r] = 0.0f; pd[r] = 0.0f;
#pragma unroll
            for (int ft = 0; ft < 4; ft++) {
                ps[r] += acc[ft][r] * as_v[ft];
                pd[r] += acc[ft][r] * ad_v[ft];
            }
        }
#pragma unroll
        for (int off = 1; off <= 8; off <<= 1)
#pragma unroll
            for (int r = 0; r < 4; r++) {
                ps[r] += __shfl_xor(ps[r], off);
                pd[r] += __shfl_xor(pd[r], off);
            }
        float vs = (l15 == 0) ? ps[0] : (l15 == 1) ? ps[1] : (l15 == 2) ? ps[2] : ps[3];
        float vd = (l15 == 0) ? pd[0] : (l15 == 1) ? pd[1] : (l15 == 2) ? pd[2] : pd[3];
        if (l15 < 4) {
            const int i = it0 + q * 4 + l15;
            e_src[(b * H_ + w) * N_ + i] = vs * LOG2E_;
            e_dst[(b * H_ + w) * N_ + i] = vd * LOG2E_;
        }
    }
}

// ---------------------------------------------------------------------------
// Kernel C (R12 attn, verbatim — best measured): i-major mask tile staged
// contiguously, es LDS-staged, hp register double-buffer, ballot-permuted
// gate bits bp0/bp1, LDS combine, normalize + bias epilogue.
// ---------------------------------------------------------------------------
__global__ __launch_bounds__(512, 4) void gat_attn_kernel(
    const unsigned int* __restrict__ mask, const unsigned short* __restrict__ hp,
    const float* __restrict__ e_src, const float* __restrict__ e_dst,
    const float* __restrict__ bias, float* __restrict__ out) {
    const int lid = ((blockIdx.x & 7) << 6) | (blockIdx.x >> 3);  // XCD swizzle
    const int b   = lid >> 5;
    const int it0 = (lid & 31) * 32;
    const int w8  = threadIdx.x >> 6;
    const int h   = w8 & 3;             // head
    const int jh  = w8 >> 2;            // j-half
    const int ln  = threadIdx.x & 63;
    const int l15 = ln & 15;
    const int q   = ln >> 4;

    __shared__ float lds[H_][2][5][64][4];   // 40 KB: acc[2][4] + accs[2]
    __shared__ float es_s[H_][N_];           // 16 KB: e_src all 4 heads
    __shared__ unsigned mk_s[32][37];        // ~4.6 KB: mask words [i'][jg], padded

    // ---- cooperative staging of es + mask tiles ----
    {
        const int tid = threadIdx.x;
#pragma unroll
        for (int p = 0; p < 2; p++) {
            const int c  = p * 512 + tid;        // 0..1023 f32x4-chunks
            const int h_ = c >> 8;
            const int of = (c & 255) * 4;
            *(f32x4*)&es_s[h_][of] =
                *(const f32x4*)(e_src + (size_t)(b * H_ + h_) * N_ + of);
        }
        if (tid < 256) {
            const int ii  = tid >> 3;            // i-row in tile
            const int jc4 = (tid & 7) * 4;       // word group
            u32x4 mv = *(const u32x4*)(mask + ((size_t)(b * N_ + it0 + ii)) * 32 + jc4);
            mk_s[ii][jc4 + 0] = mv[0];
            mk_s[ii][jc4 + 1] = mv[1];
            mk_s[ii][jc4 + 2] = mv[2];
            mk_s[ii][jc4 + 3] = mv[3];
        }
    }

    float edv[2];
    edv[0] = e_dst[(b * H_ + h) * N_ + it0 + l15];
    edv[1] = e_dst[(b * H_ + h) * N_ + it0 + 16 + l15];

    const unsigned short* hp_base = hp + (size_t)((b * H_ + h) * 32) * 2048 + ln * 8;

    f32x4 acc[2][4];
    f32x4 accs[2];
#pragma unroll
    for (int mt = 0; mt < 2; mt++) {
#pragma unroll
        for (int ft = 0; ft < 4; ft++) acc[mt][ft] = (f32x4)0.0f;
        accs[mt] = (f32x4)0.0f;
    }

    u16x8 ones_u;
#pragma unroll
    for (int jj = 0; jj < 8; jj++) ones_u[jj] = 0x3F80;   // bf16 1.0
    const bf16x8 ones = __builtin_bit_cast(bf16x8, ones_u);

    __syncthreads();   // es_s/mk_s ready

    // ---- hp register double-buffer: prefetch jg0 ----
    const unsigned short* hf0 = hp_base + (size_t)(jh * 16) * 2048;
    bf16x8 nb0 = *((const bf16x8*)(hf0 + 0 * 512));
    bf16x8 nb1 = *((const bf16x8*)(hf0 + 1 * 512));
    bf16x8 nb2 = *((const bf16x8*)(hf0 + 2 * 512));
    bf16x8 nb3 = *((const bf16x8*)(hf0 + 3 * 512));

    const int bp0[4] = {0, 16, 1, 17};
    const int bp1[4] = {8, 24, 9, 25};

#pragma unroll
    for (int t = 0; t < 16; t++) {
        const int jg = jh * 16 + t;
        const bf16x8 cb0 = nb0, cb1 = nb1, cb2 = nb2, cb3 = nb3;
        if (t < 15) {   // issue next-jg hp loads before this jg's compute
            const unsigned short* hfn = hp_base + (size_t)(jg + 1) * 2048;
            nb0 = *((const bf16x8*)(hfn + 0 * 512));
            nb1 = *((const bf16x8*)(hfn + 1 * 512));
            nb2 = *((const bf16x8*)(hfn + 2 * 512));
            nb3 = *((const bf16x8*)(hfn + 3 * 512));
        }

        f32x4 e0 = *(const f32x4*)&es_s[h][jg * 32 + q * 8];
        f32x4 e1 = *(const f32x4*)&es_s[h][jg * 32 + q * 8 + 4];
        const unsigned w0 = mk_s[l15][jg] >> (2 * q);
        const unsigned w1 = mk_s[16 + l15][jg] >> (2 * q);

        float es8[8] = {e0[0], e0[1], e0[2], e0[3], e1[0], e1[1], e1[2], e1[3]};

        bf16x8 afr[2];
#pragma unroll
        for (int mt = 0; mt < 2; mt++) {
            const unsigned mw = mt ? w1 : w0;
            u32x4 up;
#pragma unroll
            for (int p2 = 0; p2 < 4; p2++) {
                float t0 = edv[mt] + es8[2 * p2];
                float t1 = edv[mt] + es8[2 * p2 + 1];
                t0 = fmaxf(t0, NEG_ * t0);                 // leaky (log2-space)
                t1 = fmaxf(t1, NEG_ * t1);
                float p0 = __builtin_amdgcn_exp2f(t0);
                float p1 = __builtin_amdgcn_exp2f(t1);
                p0 = ((mw >> bp0[p2]) & 1u) ? p0 : 0.0f;
                p1 = ((mw >> bp1[p2]) & 1u) ? p1 : 0.0f;
                up[p2] = __builtin_amdgcn_perm(__builtin_bit_cast(unsigned, p1),
                                               __builtin_bit_cast(unsigned, p0),
                                               0x07060302u);
            }
            afr[mt] = __builtin_bit_cast(bf16x8, up);
        }
#pragma unroll
        for (int mt = 0; mt < 2; mt++) {
            acc[mt][0] = __builtin_amdgcn_mfma_f32_16x16x32_bf16(afr[mt], cb0, acc[mt][0], 0, 0, 0);
            acc[mt][1] = __builtin_amdgcn_mfma_f32_16x16x32_bf16(afr[mt], cb1, acc[mt][1], 0, 0, 0);
            acc[mt][2] = __builtin_amdgcn_mfma_f32_16x16x32_bf16(afr[mt], cb2, acc[mt][2], 0, 0, 0);
            acc[mt][3] = __builtin_amdgcn_mfma_f32_16x16x32_bf16(afr[mt], cb3, acc[mt][3], 0, 0, 0);
            accs[mt]   = __builtin_amdgcn_mfma_f32_16x16x32_bf16(afr[mt], ones, accs[mt], 0, 0, 0);
        }
    }

    // Cross-j-half combine via LDS.
    if (jh == 1) {
#pragma unroll
        for (int mt = 0; mt < 2; mt++) {
#pragma unroll
            for (int ft = 0; ft < 4; ft++)
                *(f32x4*)&lds[h][mt][ft][ln][0] = acc[mt][ft];
            *(f32x4*)&lds[h][mt][4][ln][0] = accs[mt];
        }
    }
    __syncthreads();
    if (jh == 0) {
#pragma unroll
        for (int mt = 0; mt < 2; mt++) {
#pragma unroll
            for (int ft = 0; ft < 4; ft++)
                acc[mt][ft] += *(const f32x4*)&lds[h][mt][ft][ln][0];
            accs[mt] += *(const f32x4*)&lds[h][mt][4][ln][0];
        }
        float bias_v[4];
#pragma unroll
        for (int ft = 0; ft < 4; ft++) bias_v[ft] = bias[h * F_ + ft * 16 + l15];
#pragma unroll
        for (int mt = 0; mt < 2; mt++) {
            f32x4 rinv;
#pragma unroll
            for (int r = 0; r < 4; r++) rinv[r] = 1.0f / accs[mt][r];
#pragma unroll
            for (int ft = 0; ft < 4; ft++)
#pragma unroll
                for (int r = 0; r < 4; r++) {
                    const int i = it0 + mt * 16 + q * 4 + r;
                    const int c = h * F_ + ft * 16 + l15;
                    out[(size_t)(b * N_ + i) * COUT_ + c] = acc[mt][ft][r] * rinv[r] + bias_v[ft];
                }
        }
    }
}

// ---------------------------------------------------------------------------
// Workspace layout (bytes):
//   [0, 128K)    Wtp  bf16 frag-packed [256][256]
//   [128K, +8M)  hp   bf16 frag-packed [B][H][32][4][64][8]
//   +8M: e_src f32 (256K), e_dst f32 (256K), mask u32 i-major [B][N][32] (2M).
// ---------------------------------------------------------------------------
extern "C" void kernel_launch(void* const* d_in, const int* in_sizes, int n_in,
                              void* d_out, int out_size, void* d_ws, size_t ws_size,
                              hipStream_t stream) {
    const float* x     = (const float*)d_in[0];
    const float* adj   = (const float*)d_in[1];
    const float* W     = (const float*)d_in[2];
    const float* a_src = (const float*)d_in[3];
    const float* a_dst = (const float*)d_in[4];
    const float* bias  = (const float*)d_in[5];
    float* out = (float*)d_out;

    char* ws = (char*)d_ws;
    unsigned short* Wtp = (unsigned short*)ws;
    unsigned short* hp  = (unsigned short*)(ws + 131072);
    float* e_src        = (float*)(ws + 131072 + 8388608);
    float* e_dst        = (float*)(ws + 131072 + 8388608 + 262144);
    unsigned int* mask  = (unsigned int*)(ws + 131072 + 8388608 + 524288);

    prep_kernel<<<256, 256, 0, stream>>>(W, Wtp);
    stage_kernel<<<2048, 256, 0, stream>>>(adj, x, Wtp, a_src, a_dst, mask, hp, e_src, e_dst);
    gat_attn_kernel<<<512, 512, 0, stream>>>(mask, hp, e_src, e_dst, bias, out);
}

// Round 10
// 143.191 us; speedup vs baseline: 1.0142x; 1.0027x over previous
//
#include <hip/hip_runtime.h>

// Problem constants
#define B_    16
#define N_    1024
#define DIN_  256
#define H_    4
#define F_    64
#define COUT_ 256
#define NEG_  0.2f
#define LOG2E_ 1.4426950408889634f

typedef __bf16 bf16x8 __attribute__((ext_vector_type(8)));
typedef float  f32x4  __attribute__((ext_vector_type(4)));
typedef unsigned short u16x8 __attribute__((ext_vector_type(8)));
typedef unsigned short u16x4 __attribute__((ext_vector_type(4)));
typedef unsigned int   u32x4 __attribute__((ext_vector_type(4)));

__device__ __forceinline__ unsigned short f2bf(float f) {
    unsigned u = __builtin_bit_cast(unsigned, f);
    u += 0x7fffu + ((u >> 16) & 1u);
    return (unsigned short)(u >> 16);
}

// ---------------------------------------------------------------------------
// Prep: pack W into MFMA-B-frag order Wtp, bf16 (1KB-contiguous frag loads).
// ---------------------------------------------------------------------------
__global__ __launch_bounds__(256) void prep_kernel(
    const float* __restrict__ W, unsigned short* __restrict__ Wtp) {
    const int c = blockIdx.x, k = threadIdx.x;
    const int w = c >> 6, ft = (c >> 4) & 3, l15 = c & 15;
    const int it = k >> 5, q = (k >> 3) & 3, jj = k & 7;
    const int ln = q * 16 + l15;
    Wtp[((((w * 8 + it) * 4 + ft) * 64) + ln) * 8 + jj] = f2bf(W[k * COUT_ + c]);
}

// ---------------------------------------------------------------------------
// Stage kernel — R15: exact R12 body, ONE change: __launch_bounds__(256,8).
// Evidence chain: masker stuck ~20us vs 10us stream floor across FOUR
// structural variants (R5 shuffle / R6 pipeline / R12 ballot / R14 deep
// prefetch+interleave) — in-flight-bytes, DS chains, store pattern, and
// block mixing all falsified. R5 profile: Occupancy 51% (=16 waves/CU,
// 4 blocks/CU) with VGPR=28, LDS=8.7KB — no resource explains the cap
// except the (256,4) provisioning hint. Stage hbm_gbps 1326 matches 16
// waves/CU serializing on ~1000cy latency; doubling resident waves
// doubles latency-hiding throughput directly. VGPR 28 <= 32 cap at
// (256,8) for BOTH branches (R14's 64-reg masker would spill; R12's
// 1-row masker fits) — R3 spill lesson respected. Numerics byte-identical.
// ---------------------------------------------------------------------------
__global__ __launch_bounds__(256, 8) void stage_kernel(
    const float* __restrict__ adj, const float* __restrict__ x,
    const unsigned short* __restrict__ Wtp, const float* __restrict__ a_src,
    const float* __restrict__ a_dst, unsigned int* __restrict__ mask,
    unsigned short* __restrict__ hp, float* __restrict__ e_src,
    float* __restrict__ e_dst) {
    __shared__ unsigned short xs[16][264];   // bf16 bits; padded row stride
    const int w  = threadIdx.x >> 6;
    const int ln = threadIdx.x & 63;

    if (blockIdx.x < 4096) {
        // ---- masker: 1 row/wave, ballot-based, coalesced i-major store ----
        const int row = blockIdx.x * 4 + w;          // b*N + i, 0..16383
        const float* ar = adj + (size_t)row * N_ + ln * 4;

        f32x4 v0 = *(const f32x4*)(ar);
        f32x4 v1 = *(const f32x4*)(ar + 256);
        f32x4 v2 = *(const f32x4*)(ar + 512);
        f32x4 v3 = *(const f32x4*)(ar + 768);

        // 16 ballots: bal[c][e] bit ln <-> adj[i][c*256 + ln*4 + e] > 0.5
        unsigned long long bal[4][4];
#pragma unroll
        for (int e = 0; e < 4; e++) {
            bal[0][e] = __ballot(v0[e] > 0.5f);
            bal[1][e] = __ballot(v1[e] > 0.5f);
            bal[2][e] = __ballot(v2[e] > 0.5f);
            bal[3][e] = __ballot(v3[e] > 0.5f);
        }

        // Lane ln<32 assembles word jg=ln: c=ln>>3, byte k=ln&7 of each
        // bal[c][e] -> word bit (8e+t) <-> j = jg*32 + 4t + e.
        const int c_ = (ln >> 3) & 3;
        const int sh = (ln & 7) * 8;
        unsigned wd = 0;
#pragma unroll
        for (int e = 0; e < 4; e++) {
            unsigned long long be = (c_ == 0) ? bal[0][e]
                                  : (c_ == 1) ? bal[1][e]
                                  : (c_ == 2) ? bal[2][e] : bal[3][e];
            wd |= ((unsigned)((be >> sh) & 0xffull)) << (8 * e);
        }
        if (ln < 32)
            mask[(size_t)row * 32 + ln] = wd;
    } else {
        // ---- gat_h part (bf16, R5 numerics, LDS-staged x; unchanged) ----
        const int blk = blockIdx.x - 4096;
        const int b   = blk & 15;
        const int it0 = (blk >> 4) * 16;
        const int l15 = ln & 15;
        const int q   = ln >> 4;

#pragma unroll
        for (int s = 0; s < 4; s++) {
            const int row = w * 4 + s;
            f32x4 xv = *(const f32x4*)(x + (size_t)(b * N_ + it0 + row) * DIN_ + ln * 4);
            unsigned lo = (unsigned)f2bf(xv[0]) | ((unsigned)f2bf(xv[1]) << 16);
            unsigned hi = (unsigned)f2bf(xv[2]) | ((unsigned)f2bf(xv[3]) << 16);
            unsigned long long hb = (unsigned long long)lo | ((unsigned long long)hi << 32);
            *(unsigned long long*)&xs[row][ln * 4] = hb;
        }
        __syncthreads();

        f32x4 acc[4];
#pragma unroll
        for (int ft = 0; ft < 4; ft++) acc[ft] = (f32x4)0.0f;

        const unsigned short* wb = Wtp + (w * 8) * 4 * 64 * 8 + ln * 8;
#pragma unroll
        for (int it = 0; it < 8; it++) {
            bf16x8 af = *(const bf16x8*)&xs[l15][it * 32 + q * 8];
#pragma unroll
            for (int ft = 0; ft < 4; ft++) {
                bf16x8 bf = *((const bf16x8*)(wb + (it * 4 + ft) * 512));
                acc[ft] = __builtin_amdgcn_mfma_f32_16x16x32_bf16(af, bf, acc[ft], 0, 0, 0);
            }
        }

        const int jg = it0 >> 5;
        const int q2 = 2 * ((it0 >> 4) & 1) + (q >> 1);
#pragma unroll
        for (int ft = 0; ft < 4; ft++) {
            u16x4 hb;
#pragma unroll
            for (int r = 0; r < 4; r++) hb[r] = f2bf(acc[ft][r]);
            const size_t addr =
                (size_t)((((b * H_ + w) * 32 + jg) * 4 + ft) * 64 + q2 * 16 + l15) * 8 + (q & 1) * 4;
            *((u16x4*)(hp + addr)) = hb;
        }

        float as_v[4], ad_v[4];
#pragma unroll
        for (int ft = 0; ft < 4; ft++) {
            as_v[ft] = a_src[w * F_ + ft * 16 + l15];
            ad_v[ft] = a_dst[w * F_ + ft * 16 + l15];
        }
        float ps[4], pd[4];
#pragma unroll
        for (int r = 0; r < 4; r++) {
            ps[r] = 0.0f; pd[r] = 0.0f;
#pragma unroll
            for (int ft = 0; ft < 4; ft++) {
                ps[r] += acc[ft][r] * as_v[ft];
                pd[r] += acc[ft][r] * ad_v[ft];
            }
        }
#pragma unroll
        for (int off = 1; off <= 8; off <<= 1)
#pragma unroll
            for (int r = 0; r < 4; r++) {
                ps[r] += __shfl_xor(ps[r], off);
                pd[r] += __shfl_xor(pd[r], off);
            }
        float vs = (l15 == 0) ? ps[0] : (l15 == 1) ? ps[1] : (l15 == 2) ? ps[2] : ps[3];
        float vd = (l15 == 0) ? pd[0] : (l15 == 1) ? pd[1] : (l15 == 2) ? pd[2] : pd[3];
        if (l15 < 4) {
            const int i = it0 + q * 4 + l15;
            e_src[(b * H_ + w) * N_ + i] = vs * LOG2E_;
            e_dst[(b * H_ + w) * N_ + i] = vd * LOG2E_;
        }
    }
}

// ---------------------------------------------------------------------------
// Kernel C (R12 attn, verbatim — best measured): i-major mask tile staged
// contiguously, es LDS-staged, hp register double-buffer, ballot-permuted
// gate bits bp0/bp1, LDS combine, normalize + bias epilogue.
// ---------------------------------------------------------------------------
__global__ __launch_bounds__(512, 4) void gat_attn_kernel(
    const unsigned int* __restrict__ mask, const unsigned short* __restrict__ hp,
    const float* __restrict__ e_src, const float* __restrict__ e_dst,
    const float* __restrict__ bias, float* __restrict__ out) {
    const int lid = ((blockIdx.x & 7) << 6) | (blockIdx.x >> 3);  // XCD swizzle
    const int b   = lid >> 5;
    const int it0 = (lid & 31) * 32;
    const int w8  = threadIdx.x >> 6;
    const int h   = w8 & 3;             // head
    const int jh  = w8 >> 2;            // j-half
    const int ln  = threadIdx.x & 63;
    const int l15 = ln & 15;
    const int q   = ln >> 4;

    __shared__ float lds[H_][2][5][64][4];   // 40 KB: acc[2][4] + accs[2]
    __shared__ float es_s[H_][N_];           // 16 KB: e_src all 4 heads
    __shared__ unsigned mk_s[32][37];        // ~4.6 KB: mask words [i'][jg], padded

    // ---- cooperative staging of es + mask tiles ----
    {
        const int tid = threadIdx.x;
#pragma unroll
        for (int p = 0; p < 2; p++) {
            const int c  = p * 512 + tid;        // 0..1023 f32x4-chunks
            const int h_ = c >> 8;
            const int of = (c & 255) * 4;
            *(f32x4*)&es_s[h_][of] =
                *(const f32x4*)(e_src + (size_t)(b * H_ + h_) * N_ + of);
        }
        if (tid < 256) {
            const int ii  = tid >> 3;            // i-row in tile
            const int jc4 = (tid & 7) * 4;       // word group
            u32x4 mv = *(const u32x4*)(mask + ((size_t)(b * N_ + it0 + ii)) * 32 + jc4);
            mk_s[ii][jc4 + 0] = mv[0];
            mk_s[ii][jc4 + 1] = mv[1];
            mk_s[ii][jc4 + 2] = mv[2];
            mk_s[ii][jc4 + 3] = mv[3];
        }
    }

    float edv[2];
    edv[0] = e_dst[(b * H_ + h) * N_ + it0 + l15];
    edv[1] = e_dst[(b * H_ + h) * N_ + it0 + 16 + l15];

    const unsigned short* hp_base = hp + (size_t)((b * H_ + h) * 32) * 2048 + ln * 8;

    f32x4 acc[2][4];
    f32x4 accs[2];
#pragma unroll
    for (int mt = 0; mt < 2; mt++) {
#pragma unroll
        for (int ft = 0; ft < 4; ft++) acc[mt][ft] = (f32x4)0.0f;
        accs[mt] = (f32x4)0.0f;
    }

    u16x8 ones_u;
#pragma unroll
    for (int jj = 0; jj < 8; jj++) ones_u[jj] = 0x3F80;   // bf16 1.0
    const bf16x8 ones = __builtin_bit_cast(bf16x8, ones_u);

    __syncthreads();   // es_s/mk_s ready

    // ---- hp register double-buffer: prefetch jg0 ----
    const unsigned short* hf0 = hp_base + (size_t)(jh * 16) * 2048;
    bf16x8 nb0 = *((const bf16x8*)(hf0 + 0 * 512));
    bf16x8 nb1 = *((const bf16x8*)(hf0 + 1 * 512));
    bf16x8 nb2 = *((const bf16x8*)(hf0 + 2 * 512));
    bf16x8 nb3 = *((const bf16x8*)(hf0 + 3 * 512));

    const int bp0[4] = {0, 16, 1, 17};
    const int bp1[4] = {8, 24, 9, 25};

#pragma unroll
    for (int t = 0; t < 16; t++) {
        const int jg = jh * 16 + t;
        const bf16x8 cb0 = nb0, cb1 = nb1, cb2 = nb2, cb3 = nb3;
        if (t < 15) {   // issue next-jg hp loads before this jg's compute
            const unsigned short* hfn = hp_base + (size_t)(jg + 1) * 2048;
            nb0 = *((const bf16x8*)(hfn + 0 * 512));
            nb1 = *((const bf16x8*)(hfn + 1 * 512));
            nb2 = *((const bf16x8*)(hfn + 2 * 512));
            nb3 = *((const bf16x8*)(hfn + 3 * 512));
        }

        f32x4 e0 = *(const f32x4*)&es_s[h][jg * 32 + q * 8];
        f32x4 e1 = *(const f32x4*)&es_s[h][jg * 32 + q * 8 + 4];
        const unsigned w0 = mk_s[l15][jg] >> (2 * q);
        const unsigned w1 = mk_s[16 + l15][jg] >> (2 * q);

        float es8[8] = {e0[0], e0[1], e0[2], e0[3], e1[0], e1[1], e1[2], e1[3]};

        bf16x8 afr[2];
#pragma unroll
        for (int mt = 0; mt < 2; mt++) {
            const unsigned mw = mt ? w1 : w0;
            u32x4 up;
#pragma unroll
            for (int p2 = 0; p2 < 4; p2++) {
                float t0 = edv[mt] + es8[2 * p2];
                float t1 = edv[mt] + es8[2 * p2 + 1];
                t0 = fmaxf(t0, NEG_ * t0);                 // leaky (log2-space)
                t1 = fmaxf(t1, NEG_ * t1);
                float p0 = __builtin_amdgcn_exp2f(t0);
                float p1 = __builtin_amdgcn_exp2f(t1);
                p0 = ((mw >> bp0[p2]) & 1u) ? p0 : 0.0f;
                p1 = ((mw >> bp1[p2]) & 1u) ? p1 : 0.0f;
                up[p2] = __builtin_amdgcn_perm(__builtin_bit_cast(unsigned, p1),
                                               __builtin_bit_cast(unsigned, p0),
                                               0x07060302u);
            }
            afr[mt] = __builtin_bit_cast(bf16x8, up);
        }
#pragma unroll
        for (int mt = 0; mt < 2; mt++) {
            acc[mt][0] = __builtin_amdgcn_mfma_f32_16x16x32_bf16(afr[mt], cb0, acc[mt][0], 0, 0, 0);
            acc[mt][1] = __builtin_amdgcn_mfma_f32_16x16x32_bf16(afr[mt], cb1, acc[mt][1], 0, 0, 0);
            acc[mt][2] = __builtin_amdgcn_mfma_f32_16x16x32_bf16(afr[mt], cb2, acc[mt][2], 0, 0, 0);
            acc[mt][3] = __builtin_amdgcn_mfma_f32_16x16x32_bf16(afr[mt], cb3, acc[mt][3], 0, 0, 0);
            accs[mt]   = __builtin_amdgcn_mfma_f32_16x16x32_bf16(afr[mt], ones, accs[mt], 0, 0, 0);
        }
    }

    // Cross-j-half combine via LDS.
    if (jh == 1) {
#pragma unroll
        for (int mt = 0; mt < 2; mt++) {
#pragma unroll
            for (int ft = 0; ft < 4; ft++)
                *(f32x4*)&lds[h][mt][ft][ln][0] = acc[mt][ft];
            *(f32x4*)&lds[h][mt][4][ln][0] = accs[mt];
        }
    }
    __syncthreads();
    if (jh == 0) {
#pragma unroll
        for (int mt = 0; mt < 2; mt++) {
#pragma unroll
            for (int ft = 0; ft < 4; ft++)
                acc[mt][ft] += *(const f32x4*)&lds[h][mt][ft][ln][0];
            accs[mt] += *(const f32x4*)&lds[h][mt][4][ln][0];
        }
        float bias_v[4];
#pragma unroll
        for (int ft = 0; ft < 4; ft++) bias_v[ft] = bias[h * F_ + ft * 16 + l15];
#pragma unroll
        for (int mt = 0; mt < 2; mt++) {
            f32x4 rinv;
#pragma unroll
            for (int r = 0; r < 4; r++) rinv[r] = 1.0f / accs[mt][r];
#pragma unroll
            for (int ft = 0; ft < 4; ft++)
#pragma unroll
                for (int r = 0; r < 4; r++) {
                    const int i = it0 + mt * 16 + q * 4 + r;
                    const int c = h * F_ + ft * 16 + l15;
                    out[(size_t)(b * N_ + i) * COUT_ + c] = acc[mt][ft][r] * rinv[r] + bias_v[ft];
                }
        }
    }
}

// ---------------------------------------------------------------------------
// Workspace layout (bytes):
//   [0, 128K)    Wtp  bf16 frag-packed [256][256]
//   [128K, +8M)  hp   bf16 frag-packed [B][H][32][4][64][8]
//   +8M: e_src f32 (256K), e_dst f32 (256K), mask u32 i-major [B][N][32] (2M).
// ---------------------------------------------------------------------------
extern "C" void kernel_launch(void* const* d_in, const int* in_sizes, int n_in,
                              void* d_out, int out_size, void* d_ws, size_t ws_size,
                              hipStream_t stream) {
    const float* x     = (const float*)d_in[0];
    const float* adj   = (const float*)d_in[1];
    const float* W     = (const float*)d_in[2];
    const float* a_src = (const float*)d_in[3];
    const float* a_dst = (const float*)d_in[4];
    const float* bias  = (const float*)d_in[5];
    float* out = (float*)d_out;

    char* ws = (char*)d_ws;
    unsigned short* Wtp = (unsigned short*)ws;
    unsigned short* hp  = (unsigned short*)(ws + 131072);
    float* e_src        = (float*)(ws + 131072 + 8388608);
    float* e_dst        = (float*)(ws + 131072 + 8388608 + 262144);
    unsigned int* mask  = (unsigned int*)(ws + 131072 + 8388608 + 524288);

    prep_kernel<<<256, 256, 0, stream>>>(W, Wtp);
    stage_kernel<<<5120, 256, 0, stream>>>(adj, x, Wtp, a_src, a_dst, mask, hp, e_src, e_dst);
    gat_attn_kernel<<<512, 512, 0, stream>>>(mask, hp, e_src, e_dst, bias, out);
}